// Round 13
// baseline (83.306 us; speedup 1.0000x reference)
//
#include <hip/hip_runtime.h>
#include <math.h>

#define N_IMG 512
#define N_ANGLES 25
#define N_DET 512
#define DET_SPACING 3.0f
#define SRC_DIST 512.0f
#define DET_DIST 512.0f
#define N_SAMPLES 1024
#define QP 258            // quad patches per side (covers r,c in [-2, 513])

// ws: 4.26 MB padded, 2x2-blocked quad array (see R12 notes).
__device__ __forceinline__ int quad_idx(int R, int C) {
    return ((((R >> 1) * QP) + (C >> 1)) << 2) + ((R & 1) << 1) + (C & 1);
}

__device__ __forceinline__ float img_at(const float* __restrict__ img, int r, int c) {
    return ((unsigned)r < N_IMG && (unsigned)c < N_IMG) ? img[(r << 9) + c] : 0.0f;
}

__global__ __launch_bounds__(256) void build_quads(const float* __restrict__ img,
                                                   float4* __restrict__ quad) {
    int idx = blockIdx.x * 256 + (int)threadIdx.x;     // covers R,C in [0,515]
    if (idx >= 516 * 516) return;
    int R = idx / 516, C = idx - R * 516;
    int r = R - 2, c = C - 2;
    float4 q;
    q.x = img_at(img, r,     c);
    q.y = img_at(img, r,     c + 1);
    q.z = img_at(img, r + 1, c);
    q.w = img_at(img, r + 1, c + 1);
    quad[quad_idx(R, C)] = q;
}

__device__ __forceinline__ void slab(float v0, float dv, float lo, float hi,
                                     float& tlo, float& thi) {
    if (fabsf(dv) < 1e-8f) {
        if (v0 < lo || v0 > hi) { tlo = 1.0f; thi = 0.0f; }
    } else {
        float inv = 1.0f / dv;
        float ta = (lo - v0) * inv;
        float tb = (hi - v0) * inv;
        tlo = fmaxf(tlo, fminf(ta, tb));
        thi = fminf(thi, fmaxf(ta, tb));
    }
}

__device__ __forceinline__ void sample_addr(float col0, float dx, float row0,
                                            float drow, int i,
                                            int& idx, float& fc, float& fr) {
    float ts  = ((float)i + 0.5f) * (1.0f / N_SAMPLES);
    float col = fmaf(ts, dx,   col0);
    float row = fmaf(ts, drow, row0);
    float cf = floorf(col), rf = floorf(row);
    fc = col - cf;  fr = row - rf;
    int Ci = min(max((int)cf + 2, 0), 514);
    int Ri = min(max((int)rf + 2, 0), 514);
    idx = quad_idx(Ri, Ci);
}

__device__ __forceinline__ float bil(float4 q, float fc, float fr) {
    float top = fmaf(fc, q.y - q.x, q.x);
    float bot = fmaf(fc, q.w - q.z, q.z);
    return fmaf(fr, bot - top, top);
}

__global__ __launch_bounds__(256) void fanbeam_kernel(const float4* __restrict__ quad,
                                                      float* __restrict__ out) {
    const int gid  = blockIdx.x * 256 + (int)threadIdx.x;
    const int ray  = gid >> 6;
    const int lane = (int)threadIdx.x & 63;
    if (ray >= N_ANGLES * N_DET) return;

    const int a = ray >> 9;
    const int d = ray & 511;

    float beta = (2.0f * (float)a / 25.0f) * 3.14159265358979323846f;
    float c, s;
    __sincosf(beta, &s, &c);
    float t = ((float)d - (N_DET - 1) * 0.5f) * DET_SPACING;
    float srcx = -SRC_DIST * s;
    float srcy =  SRC_DIST * c;
    float dx = (t * c + DET_DIST * s) - srcx;
    float dy = (t * s - DET_DIST * c) - srcy;
    float seg = sqrtf(dx * dx + dy * dy);

    const float half = (N_IMG - 1) * 0.5f;
    const float col0 = srcx + half;
    const float row0 = half - srcy;
    const float drow = -dy;

    float tA = 0.0f, tB = 1.0f;
    slab(col0, dx,   -1.01f, 512.01f, tA, tB);
    slab(row0, drow, -1.01f, 512.01f, tA, tB);

    float acc = 0.0f;
    if (tA <= tB) {
        int i_lo = max(0,             (int)floorf(tA * N_SAMPLES - 0.5f) - 1);
        int i_hi = min(N_SAMPLES - 1, (int)ceilf (tB * N_SAMPLES - 0.5f) + 1);
        int n = i_hi - i_lo + 1;
        int k = 0;
        for (; k + 256 <= n; k += 256) {
            int i0 = i_lo + k + lane;
            int x0, x1, x2, x3; float a0,a1,a2,a3,b0,b1,b2,b3;
            sample_addr(col0, dx, row0, drow, i0,       x0, a0, b0);
            sample_addr(col0, dx, row0, drow, i0 + 64,  x1, a1, b1);
            sample_addr(col0, dx, row0, drow, i0 + 128, x2, a2, b2);
            sample_addr(col0, dx, row0, drow, i0 + 192, x3, a3, b3);
            float4 q0 = quad[x0];
            float4 q1 = quad[x1];
            float4 q2 = quad[x2];
            float4 q3 = quad[x3];
            acc += bil(q0, a0, b0) + bil(q1, a1, b1)
                 + bil(q2, a2, b2) + bil(q3, a3, b3);
        }
        if (k < n) {
            int i0 = i_lo + k + lane;
            int r0 = k + lane, rem = n;
            int x0, x1, x2, x3; float a0,a1,a2,a3,b0,b1,b2,b3;
            sample_addr(col0, dx, row0, drow, i0,       x0, a0, b0);
            sample_addr(col0, dx, row0, drow, i0 + 64,  x1, a1, b1);
            sample_addr(col0, dx, row0, drow, i0 + 128, x2, a2, b2);
            sample_addr(col0, dx, row0, drow, i0 + 192, x3, a3, b3);
            x0 = (r0       < rem) ? x0 : 0;
            x1 = (r0 + 64  < rem) ? x1 : 0;
            x2 = (r0 + 128 < rem) ? x2 : 0;
            x3 = (r0 + 192 < rem) ? x3 : 0;
            float4 q0 = quad[x0];
            float4 q1 = quad[x1];
            float4 q2 = quad[x2];
            float4 q3 = quad[x3];
            acc += bil(q0, a0, b0) + bil(q1, a1, b1)
                 + bil(q2, a2, b2) + bil(q3, a3, b3);
        }
    }

    #pragma unroll
    for (int off = 32; off > 0; off >>= 1)
        acc += __shfl_down(acc, off, 64);

    if (lane == 0) out[ray] = acc * (seg * (1.0f / N_SAMPLES));
}

extern "C" void kernel_launch(void* const* d_in, const int* in_sizes, int n_in,
                              void* d_out, int out_size, void* d_ws, size_t ws_size,
                              hipStream_t stream) {
    const float* img = (const float*)d_in[0];
    float* out = (float*)d_out;
    float4* quad = (float4*)d_ws;                  // 258*258*4*16 B = 4.26 MB

    build_quads<<<(516 * 516 + 255) / 256, 256, 0, stream>>>(img, quad);

    const int n_rays = N_ANGLES * N_DET;           // 12800, one wave each
    // DIAGNOSTIC: dispatch the projector TWICE (idempotent — second pass
    // overwrites identical values).  Delta vs R12's 71.1 us measures the
    // true per-dispatch cost of this kernel, discriminating "kernel is
    // really ~20 us" (total -> ~91) from "kernel ~5 us + fixed harness
    // overhead" (total -> ~76).
    fanbeam_kernel<<<n_rays * 64 / 256, 256, 0, stream>>>(quad, out);
    fanbeam_kernel<<<n_rays * 64 / 256, 256, 0, stream>>>(quad, out);
}

// Round 14
// 74.115 us; speedup vs baseline: 1.1240x; 1.1240x over previous
//
#include <hip/hip_runtime.h>
#include <math.h>

#define N_IMG 512
#define N_ANGLES 25
#define N_DET 512
#define DET_SPACING 3.0f
#define SRC_DIST 512.0f
#define DET_DIST 512.0f
#define N_SAMPLES 1024
#define PAD 8
#define QW 528            // patch grid side: r,c in [-8, 519]

// ---------------------------------------------------------------------------
// ws: 4.46 MB padded quad array, plain row-major.
//   quad[R*528+C] = {v(r,c), v(r,c+1), v(r+1,c), v(r+1,c+1)},  r=R-8, c=C-8,
//   v = img inside, 0 outside.  Bilinear on a quad == the reference's
//   per-corner masked bilinear for ALL sample positions (each invalid corner
//   contributes exactly 0).  8-px zero pad makes every sample in the clipped
//   window (max step 1.25 px, +-2.5-sample margin => <=3.2 px overshoot)
//   provably in-range: NO clamps in the hot loop.
// ---------------------------------------------------------------------------
__device__ __forceinline__ float img_at(const float* __restrict__ img, int r, int c) {
    return ((unsigned)r < N_IMG && (unsigned)c < N_IMG) ? img[(r << 9) + c] : 0.0f;
}

__global__ __launch_bounds__(256) void build_quads(const float* __restrict__ img,
                                                   float4* __restrict__ quad) {
    int idx = blockIdx.x * 256 + (int)threadIdx.x;
    if (idx >= QW * QW) return;
    int R = idx / QW, C = idx - R * QW;
    int r = R - PAD, c = C - PAD;
    float4 q;
    q.x = img_at(img, r,     c);
    q.y = img_at(img, r,     c + 1);
    q.z = img_at(img, r + 1, c);
    q.w = img_at(img, r + 1, c + 1);
    quad[idx] = q;           // coalesced write
}

// Clip [tlo,thi] to { t : lo <= v0 + t*dv <= hi }.
__device__ __forceinline__ void slab(float v0, float dv, float lo, float hi,
                                     float& tlo, float& thi) {
    if (fabsf(dv) < 1e-8f) {
        if (v0 < lo || v0 > hi) { tlo = 1.0f; thi = 0.0f; }
    } else {
        float inv = 1.0f / dv;
        float ta = (lo - v0) * inv;
        float tb = (hi - v0) * inv;
        tlo = fmaxf(tlo, fminf(ta, tb));
        thi = fminf(thi, fmaxf(ta, tb));
    }
}

__device__ __forceinline__ float bil(float4 q, float fc, float fr) {
    float top = fmaf(fc, q.y - q.x, q.x);
    float bot = fmaf(fc, q.w - q.z, q.z);
    return fmaf(fr, bot - top, top);
}

// One wave per ray; 4-deep batched loads; clamp-free minimal-VALU inner loop.
__global__ __launch_bounds__(256) void fanbeam_kernel(const float4* __restrict__ quad,
                                                      float* __restrict__ out) {
    const int gid  = blockIdx.x * 256 + (int)threadIdx.x;
    const int ray  = gid >> 6;
    const int lane = (int)threadIdx.x & 63;
    if (ray >= N_ANGLES * N_DET) return;

    const int a = ray >> 9;
    const int d = ray & 511;

    float beta = (2.0f * (float)a / 25.0f) * 3.14159265358979323846f;
    float c, s;
    __sincosf(beta, &s, &c);
    float t = ((float)d - (N_DET - 1) * 0.5f) * DET_SPACING;
    float srcx = -SRC_DIST * s;
    float srcy =  SRC_DIST * c;
    float dx = (t * c + DET_DIST * s) - srcx;
    float dy = (t * s - DET_DIST * c) - srcy;
    float seg = sqrtf(dx * dx + dy * dy);

    const float half = (N_IMG - 1) * 0.5f;
    const float col0 = srcx + half;            // unpadded (for clipping)
    const float row0 = half - srcy;
    const float drow = -dy;
    const float col0p = col0 + (float)PAD;     // padded-coordinate origins
    const float row0p = row0 + (float)PAD;
    const float inv_n  = 1.0f / N_SAMPLES;
    const float hinv_n = 0.5f / N_SAMPLES;

    float tA = 0.0f, tB = 1.0f;
    slab(col0, dx,   -1.01f, 512.01f, tA, tB);
    slab(row0, drow, -1.01f, 512.01f, tA, tB);

    float acc = 0.0f;
    if (tA <= tB) {
        int i_lo = max(0,             (int)floorf(tA * N_SAMPLES - 0.5f) - 1);
        int i_hi = min(N_SAMPLES - 1, (int)ceilf (tB * N_SAMPLES - 0.5f) + 1);
        int n = i_hi - i_lo + 1;                       // wave-uniform
        int k = 0;
        // 4-deep batches: 4 independent loads in flight, no clamps, 1-mad idx.
        for (; k + 256 <= n; k += 256) {
            float f0 = (float)(i_lo + k + lane);       // exact in fp32
            float acc4 = 0.0f;
            #pragma unroll
            for (int j = 0; j < 4; ++j) {
                float ts  = fmaf(f0 + 64.0f * j, inv_n, hinv_n);
                float col = fmaf(ts, dx,   col0p);
                float row = fmaf(ts, drow, row0p);
                float cf = floorf(col), rf = floorf(row);
                float fc = col - cf,    fr = row - rf;
                int idx = (int)rf * QW + (int)cf;      // mad_u32_u24
                float4 q = quad[idx];
                acc4 += bil(q, fc, fr);
            }
            acc += acc4;
        }
        // Tail (< 4 strides): plain loop, still clamp-free (i <= i_hi).
        #pragma unroll 2
        for (int i = i_lo + k + lane; i <= i_hi; i += 64) {
            float ts  = fmaf((float)i, inv_n, hinv_n);
            float col = fmaf(ts, dx,   col0p);
            float row = fmaf(ts, drow, row0p);
            float cf = floorf(col), rf = floorf(row);
            float fc = col - cf,    fr = row - rf;
            int idx = (int)rf * QW + (int)cf;
            float4 q = quad[idx];
            acc += bil(q, fc, fr);
        }
    }

    #pragma unroll
    for (int off = 32; off > 0; off >>= 1)
        acc += __shfl_down(acc, off, 64);

    if (lane == 0) out[ray] = acc * (seg * inv_n);
}

extern "C" void kernel_launch(void* const* d_in, const int* in_sizes, int n_in,
                              void* d_out, int out_size, void* d_ws, size_t ws_size,
                              hipStream_t stream) {
    const float* img = (const float*)d_in[0];
    float* out = (float*)d_out;
    float4* quad = (float4*)d_ws;                  // 528*528*16 B = 4.46 MB

    build_quads<<<(QW * QW + 255) / 256, 256, 0, stream>>>(img, quad);

    const int n_rays = N_ANGLES * N_DET;           // 12800, one wave each
    fanbeam_kernel<<<n_rays * 64 / 256, 256, 0, stream>>>(quad, out);
}

// Round 15
// 70.969 us; speedup vs baseline: 1.1738x; 1.0443x over previous
//
#include <hip/hip_runtime.h>
#include <math.h>

#define N_IMG 512
#define N_ANGLES 25
#define N_DET 512
#define DET_SPACING 3.0f
#define SRC_DIST 512.0f
#define DET_DIST 512.0f
#define N_SAMPLES 1024
#define PAD 8
#define QW 528            // patch grid side: r,c in [-8, 519]
#define QP 264            // patch-pairs per side (QW/2)

// ---------------------------------------------------------------------------
// ws: 4.46 MB zero-padded, 2x2-BLOCKED quad array.
//   quad(r,c) = {v(r,c), v(r,c+1), v(r+1,c), v(r+1,c+1)},  v = img inside,
//   0 outside -> bilinear on quads == reference's per-corner masking.
//   R=r+PAD, C=c+PAD in [0,527]; idx = (((R>>1)*QP + (C>>1))<<2)+((R&1)<<1)+(C&1)
//   One 64 B line = 2x2-pixel patch -> ~0.6 unique lines/sample any direction
//   (R12-measured TA side), while the 8-px pad removes all clamps from the
//   hot loop (R14-measured VALU side).  fanbeam = max(VALU, TA); this takes
//   the min of both prior kernels.
// ---------------------------------------------------------------------------
__device__ __forceinline__ int quad_idx(int R, int C) {
    return ((((R >> 1) * QP) + (C >> 1)) << 2) + ((R & 1) << 1) + (C & 1);
}

__device__ __forceinline__ float img_at(const float* __restrict__ img, int r, int c) {
    return ((unsigned)r < N_IMG && (unsigned)c < N_IMG) ? img[(r << 9) + c] : 0.0f;
}

__global__ __launch_bounds__(256) void build_quads(const float* __restrict__ img,
                                                   float4* __restrict__ quad) {
    int idx = blockIdx.x * 256 + (int)threadIdx.x;
    if (idx >= QW * QW) return;
    int R = idx / QW, C = idx - R * QW;
    int r = R - PAD, c = C - PAD;
    float4 q;
    q.x = img_at(img, r,     c);
    q.y = img_at(img, r,     c + 1);
    q.z = img_at(img, r + 1, c);
    q.w = img_at(img, r + 1, c + 1);
    quad[quad_idx(R, C)] = q;
}

// Clip [tlo,thi] to { t : lo <= v0 + t*dv <= hi }.
__device__ __forceinline__ void slab(float v0, float dv, float lo, float hi,
                                     float& tlo, float& thi) {
    if (fabsf(dv) < 1e-8f) {
        if (v0 < lo || v0 > hi) { tlo = 1.0f; thi = 0.0f; }
    } else {
        float inv = 1.0f / dv;
        float ta = (lo - v0) * inv;
        float tb = (hi - v0) * inv;
        tlo = fmaxf(tlo, fminf(ta, tb));
        thi = fminf(thi, fmaxf(ta, tb));
    }
}

__device__ __forceinline__ float bil(float4 q, float fc, float fr) {
    float top = fmaf(fc, q.y - q.x, q.x);
    float bot = fmaf(fc, q.w - q.z, q.z);
    return fmaf(fr, bot - top, top);
}

// One wave per ray; 4-deep batched loads; clamp-free blocked-index inner loop.
__global__ __launch_bounds__(256) void fanbeam_kernel(const float4* __restrict__ quad,
                                                      float* __restrict__ out) {
    const int gid  = blockIdx.x * 256 + (int)threadIdx.x;
    const int ray  = gid >> 6;
    const int lane = (int)threadIdx.x & 63;
    if (ray >= N_ANGLES * N_DET) return;

    const int a = ray >> 9;
    const int d = ray & 511;

    float beta = (2.0f * (float)a / 25.0f) * 3.14159265358979323846f;
    float c, s;
    __sincosf(beta, &s, &c);
    float t = ((float)d - (N_DET - 1) * 0.5f) * DET_SPACING;
    float srcx = -SRC_DIST * s;
    float srcy =  SRC_DIST * c;
    float dx = (t * c + DET_DIST * s) - srcx;
    float dy = (t * s - DET_DIST * c) - srcy;
    float seg = sqrtf(dx * dx + dy * dy);

    const float half = (N_IMG - 1) * 0.5f;
    const float col0 = srcx + half;            // unpadded (for clipping)
    const float row0 = half - srcy;
    const float drow = -dy;
    const float col0p = col0 + (float)PAD;     // padded-coordinate origins
    const float row0p = row0 + (float)PAD;
    const float inv_n = 1.0f / N_SAMPLES;

    float tA = 0.0f, tB = 1.0f;
    slab(col0, dx,   -1.01f, 512.01f, tA, tB);
    slab(row0, drow, -1.01f, 512.01f, tA, tB);

    float acc = 0.0f;
    if (tA <= tB) {
        int i_lo = max(0,             (int)floorf(tA * N_SAMPLES - 0.5f) - 1);
        int i_hi = min(N_SAMPLES - 1, (int)ceilf (tB * N_SAMPLES - 0.5f) + 1);
        int n = i_hi - i_lo + 1;                       // wave-uniform
        int k = 0;
        // 4-deep batches: 4 independent loads in flight; padded coords are
        // always >= ~4 within the window, so trunc == floor and no clamps.
        for (; k + 256 <= n; k += 256) {
            float f0 = (float)(i_lo + k + lane);       // exact in fp32
            float acc4 = 0.0f;
            #pragma unroll
            for (int j = 0; j < 4; ++j) {
                float ts  = (f0 + (64.0f * j + 0.5f)) * inv_n;
                float col = fmaf(ts, dx,   col0p);
                float row = fmaf(ts, drow, row0p);
                float cf = floorf(col), rf = floorf(row);
                float fc = col - cf,    fr = row - rf;
                float4 q = quad[quad_idx((int)rf, (int)cf)];
                acc4 += bil(q, fc, fr);
            }
            acc += acc4;
        }
        // Tail (< 4 strides): plain loop, still clamp-free.
        #pragma unroll 2
        for (int i = i_lo + k + lane; i <= i_hi; i += 64) {
            float ts  = ((float)i + 0.5f) * inv_n;
            float col = fmaf(ts, dx,   col0p);
            float row = fmaf(ts, drow, row0p);
            float cf = floorf(col), rf = floorf(row);
            float fc = col - cf,    fr = row - rf;
            float4 q = quad[quad_idx((int)rf, (int)cf)];
            acc += bil(q, fc, fr);
        }
    }

    #pragma unroll
    for (int off = 32; off > 0; off >>= 1)
        acc += __shfl_down(acc, off, 64);

    if (lane == 0) out[ray] = acc * (seg * inv_n);
}

extern "C" void kernel_launch(void* const* d_in, const int* in_sizes, int n_in,
                              void* d_out, int out_size, void* d_ws, size_t ws_size,
                              hipStream_t stream) {
    const float* img = (const float*)d_in[0];
    float* out = (float*)d_out;
    float4* quad = (float4*)d_ws;                  // 528*528*16 B = 4.46 MB

    build_quads<<<(QW * QW + 255) / 256, 256, 0, stream>>>(img, quad);

    const int n_rays = N_ANGLES * N_DET;           // 12800, one wave each
    fanbeam_kernel<<<n_rays * 64 / 256, 256, 0, stream>>>(quad, out);
}